// Round 2
// baseline (219.515 us; speedup 1.0000x reference)
//
#include <hip/hip_runtime.h>

#define TT 140
#define BB 8192
#define HH 64
#define BT 16   // batch tile per block (MFMA N)
#define HS 72   // h-array stride in bf16 elems (144 B = 16B-aligned b128 frags)
#define FP ((TT - 1) & 1)   // parity of final step (=1)

typedef __bf16 bf16x8 __attribute__((ext_vector_type(8)));
typedef __bf16 bf16x4 __attribute__((ext_vector_type(4)));
typedef float  f32x4  __attribute__((ext_vector_type(4)));

#define MFMA(a,b,c) __builtin_amdgcn_mfma_f32_16x16x32_bf16(a, b, c, 0, 0, 0)

__device__ __forceinline__ float fast_tanh(float a) {
    float e = __builtin_amdgcn_exp2f(a * 2.88539008178f);
    return 1.0f - 2.0f * __builtin_amdgcn_rcpf(e + 1.0f);
}

// 16B-aligned LDS fragment load -> single ds_read_b128
__device__ __forceinline__ bf16x8 ld_frag(const __bf16* p) {
    return *(const bf16x8*)__builtin_assume_aligned(p, 16);
}

__device__ __forceinline__ void cvt_frag(const float* p, bf16x8& hi, bf16x8& lo) {
    f32x4 wa = *(const f32x4*)p;
    f32x4 wb = *(const f32x4*)(p + 4);
    #pragma unroll
    for (int j = 0; j < 8; ++j) {
        float f = (j < 4) ? wa[j] : wb[j - 4];
        __bf16 h = (__bf16)f;
        hi[j] = h;
        lo[j] = (__bf16)(f - (float)h);
    }
}

// 2-wave pipeline: wave 0 = full layer0 (step p), wave 1 = full layer1
// (step p-1). Each wave owns ALL 64 units of its layer for the 16-batch
// tile, so every LDS H-fragment is read exactly once per consumer (minimum
// possible LDS traffic), and layer1 produces the finished output projection
// itself (no partial buffer / folder wave).
__global__ __launch_bounds__(128, 1)
void rnn_kernel(const float* __restrict__ x,
                const float* __restrict__ h_state,
                const float* __restrict__ W_ih0,
                const float* __restrict__ W_hh0,
                const float* __restrict__ b_ih0,
                const float* __restrict__ b_hh0,
                const float* __restrict__ W_ih1,
                const float* __restrict__ W_hh1,
                const float* __restrict__ b_ih1,
                const float* __restrict__ b_hh1,
                const float* __restrict__ W_out,
                const float* __restrict__ b_out,
                float* __restrict__ out)
{
    __shared__ __align__(16) __bf16 h0hi[2][BT * HS], h0lo[2][BT * HS];
    __shared__ __align__(16) __bf16 h1hi[2][BT * HS], h1lo[2][BT * HS];
    __shared__ float  xs[TT * 17];     // x staged [t][b]
    __shared__ float  outs[TT * 17];   // y staged [t][b]

    const int tid  = threadIdx.x;
    const int w    = tid >> 6;        // 0 = layer0 wave, 1 = layer1 wave
    const int lane = tid & 63;
    const int col  = lane & 15;       // MFMA col (batch)
    const int q    = lane >> 4;       // quad
    const int b0   = blockIdx.x * BT;

    // ---- A-fragments: [g][kt]; layer0 uses kt 0..1 (Whh0), layer1 kt 0..1 =
    //      Wih1, kt 2..3 = Whh1. hi/lo split (compensated bf16, identical
    //      numerics to the verified kernel).
    bf16x8 AFh[4][4], AFl[4][4];
    if (w == 0) {
        #pragma unroll
        for (int g = 0; g < 4; ++g)
        #pragma unroll
        for (int kt = 0; kt < 2; ++kt) {
            const int off = (16 * g + col) * HH + 32 * kt + 8 * q;
            cvt_frag(W_hh0 + off, AFh[g][kt], AFl[g][kt]);
        }
    } else {
        #pragma unroll
        for (int g = 0; g < 4; ++g)
        #pragma unroll
        for (int kt = 0; kt < 2; ++kt) {
            const int off = (16 * g + col) * HH + 32 * kt + 8 * q;
            cvt_frag(W_ih1 + off, AFh[g][kt],     AFl[g][kt]);
            cvt_frag(W_hh1 + off, AFh[g][2 + kt], AFl[g][2 + kt]);
        }
    }
    // epilogue scalars: layer0: e0=bias0, e1=Wih0 ; layer1: e0=bias1, e1=Wout
    float e0[4][4], e1[4][4];
    #pragma unroll
    for (int g = 0; g < 4; ++g)
    #pragma unroll
    for (int r = 0; r < 4; ++r) {
        int j = 16 * g + 4 * q + r;
        if (w == 0) { e0[g][r] = b_ih0[j] + b_hh0[j]; e1[g][r] = W_ih0[j]; }
        else        { e0[g][r] = b_ih1[j] + b_hh1[j]; e1[g][r] = W_out[j]; }
    }
    const float bout = b_out[0];

    // ---- stage x[b0..b0+15][0..139] into LDS [t][b] (128 threads) ----
    for (int c = 0; c < (TT * BT + 127) / 128; ++c) {
        int i = c * 128 + tid;
        if (i < TT * BT) {
            int t = i >> 4, b = i & 15;
            xs[t * 17 + b] = x[(size_t)(b0 + b) * TT + t];
        }
    }
    // ---- init hidden state ([2,B,H]) into parity-1 buffers (step "-1") ----
    #pragma unroll
    for (int c = 0; c < (BT * HH) / 128; ++c) {
        int i = c * 128 + tid;
        int b = i >> 6, u = i & 63;
        float v0 = h_state[(size_t)(b0 + b) * HH + u];
        float v1 = h_state[(size_t)BB * HH + (size_t)(b0 + b) * HH + u];
        __bf16 c0 = (__bf16)v0;
        h0hi[1][b * HS + u] = c0;
        h0lo[1][b * HS + u] = (__bf16)(v0 - (float)c0);
        __bf16 c1 = (__bf16)v1;
        h1hi[1][b * HS + u] = c1;
        h1lo[1][b * HS + u] = (__bf16)(v1 - (float)c1);
    }
    __syncthreads();

    // ---- pipelined phase loop: p=0..TT ----
    for (int p = 0; p <= TT; ++p) {
        if (w == 0) {
            if (p < TT) {
                // layer0 step p: read h0(p-1) parity (p+1)&1, write parity p&1
                const int rb = (p + 1) & 1, wb = p & 1;
                bf16x8 Hh[2], Hl[2];
                #pragma unroll
                for (int kt = 0; kt < 2; ++kt) {
                    Hh[kt] = ld_frag(&h0hi[rb][col * HS + 32 * kt + 8 * q]);
                    Hl[kt] = ld_frag(&h0lo[rb][col * HS + 32 * kt + 8 * q]);
                }
                float xt = xs[p * 17 + col];
                #pragma unroll
                for (int g = 0; g < 4; ++g) {
                    f32x4 c0 = {0.f,0.f,0.f,0.f}, c1 = {0.f,0.f,0.f,0.f}, c2 = {0.f,0.f,0.f,0.f};
                    #pragma unroll
                    for (int kt = 0; kt < 2; ++kt) {
                        c0 = MFMA(AFh[g][kt], Hh[kt], c0);   // hi*hi
                        c1 = MFMA(AFh[g][kt], Hl[kt], c1);   // hi*lo
                        c2 = MFMA(AFl[g][kt], Hh[kt], c2);   // lo*hi
                    }
                    f32x4 a = c0 + (c1 + c2);
                    bf16x4 hi4, lo4;
                    #pragma unroll
                    for (int r = 0; r < 4; ++r) {
                        float pre = a[r] + e0[g][r] + e1[g][r] * xt;
                        float hn  = fast_tanh(pre);
                        __bf16 h  = (__bf16)hn;
                        hi4[r] = h;
                        lo4[r] = (__bf16)(hn - (float)h);
                    }
                    *(bf16x4*)(&h0hi[wb][col * HS + 16 * g + 4 * q]) = hi4;
                    *(bf16x4*)(&h0lo[wb][col * HS + 16 * g + 4 * q]) = lo4;
                }
            }
        } else {
            if (p >= 1) {
                // layer1 step s=p-1: read h0n(s) parity s&1 (written by wave0
                // last phase), h1(s-1) parity (s+1)&1; write h1(s) parity s&1
                const int s   = p - 1;
                const int rb0 = s & 1, rb1 = (s + 1) & 1, wb1 = s & 1;
                bf16x8 Hh[4], Hl[4];
                #pragma unroll
                for (int kt = 0; kt < 2; ++kt) {
                    Hh[kt]     = ld_frag(&h0hi[rb0][col * HS + 32 * kt + 8 * q]);
                    Hl[kt]     = ld_frag(&h0lo[rb0][col * HS + 32 * kt + 8 * q]);
                    Hh[2 + kt] = ld_frag(&h1hi[rb1][col * HS + 32 * kt + 8 * q]);
                    Hl[2 + kt] = ld_frag(&h1lo[rb1][col * HS + 32 * kt + 8 * q]);
                }
                float pr = 0.f;
                #pragma unroll
                for (int g = 0; g < 4; ++g) {
                    f32x4 c0 = {0.f,0.f,0.f,0.f}, c1 = {0.f,0.f,0.f,0.f}, c2 = {0.f,0.f,0.f,0.f};
                    #pragma unroll
                    for (int kt = 0; kt < 4; ++kt) {
                        c0 = MFMA(AFh[g][kt], Hh[kt], c0);
                        c1 = MFMA(AFh[g][kt], Hl[kt], c1);
                        c2 = MFMA(AFl[g][kt], Hh[kt], c2);
                    }
                    f32x4 a = c0 + (c1 + c2);
                    bf16x4 hi4, lo4;
                    #pragma unroll
                    for (int r = 0; r < 4; ++r) {
                        float pre = a[r] + e0[g][r];
                        float hn  = fast_tanh(pre);
                        pr += hn * e1[g][r];
                        __bf16 h = (__bf16)hn;
                        hi4[r] = h;
                        lo4[r] = (__bf16)(hn - (float)h);
                    }
                    *(bf16x4*)(&h1hi[wb1][col * HS + 16 * g + 4 * q]) = hi4;
                    *(bf16x4*)(&h1lo[wb1][col * HS + 16 * g + 4 * q]) = lo4;
                }
                // full 64-unit projection: sum the q-quadrants
                pr += __shfl_xor(pr, 16, 64);
                pr += __shfl_xor(pr, 32, 64);
                if (lane < 16) outs[s * 17 + lane] = pr + bout;
            }
        }
        __syncthreads();
    }

    // ---- epilogue: staged y -> global; wave w does batches {2*bq + w} ----
    #pragma unroll
    for (int bq = 0; bq < 8; ++bq) {
        int b = 2 * bq + w;
        #pragma unroll
        for (int c = 0; c < 3; ++c) {
            int t = c * 64 + lane;
            if (t < TT) out[(size_t)(b0 + b) * TT + t] = outs[t * 17 + b];
        }
    }
    // ---- h_final: [2,B,H] appended after out[B*T]; final parity FP ----
    const size_t OFF = (size_t)BB * TT;
    #pragma unroll
    for (int c = 0; c < (BT * HH) / 128; ++c) {
        int i = c * 128 + tid;
        int b = i >> 6, u = i & 63;
        float v0 = (float)h0hi[FP][b * HS + u] + (float)h0lo[FP][b * HS + u];
        float v1 = (float)h1hi[FP][b * HS + u] + (float)h1lo[FP][b * HS + u];
        out[OFF + (size_t)(b0 + b) * HH + u] = v0;
        out[OFF + (size_t)BB * HH + (size_t)(b0 + b) * HH + u] = v1;
    }
}

extern "C" void kernel_launch(void* const* d_in, const int* in_sizes, int n_in,
                              void* d_out, int out_size, void* d_ws, size_t ws_size,
                              hipStream_t stream) {
    const float* x      = (const float*)d_in[0];
    const float* hst    = (const float*)d_in[1];
    const float* W_ih0  = (const float*)d_in[2];
    const float* W_hh0  = (const float*)d_in[3];
    const float* b_ih0  = (const float*)d_in[4];
    const float* b_hh0  = (const float*)d_in[5];
    const float* W_ih1  = (const float*)d_in[6];
    const float* W_hh1  = (const float*)d_in[7];
    const float* b_ih1  = (const float*)d_in[8];
    const float* b_hh1  = (const float*)d_in[9];
    const float* W_out  = (const float*)d_in[10];
    const float* b_outp = (const float*)d_in[11];
    float* out = (float*)d_out;

    dim3 grid(BB / BT);   // 512 blocks x 2 waves = 1024 waves (4/CU at 2 blk/CU)
    dim3 block(128);
    rnn_kernel<<<grid, block, 0, stream>>>(x, hst, W_ih0, W_hh0, b_ih0, b_hh0,
                                           W_ih1, W_hh1, b_ih1, b_hh1,
                                           W_out, b_outp, out);
}

// Round 3
// 211.073 us; speedup vs baseline: 1.0400x; 1.0400x over previous
//
#include <hip/hip_runtime.h>

#define TT 140
#define BB 8192
#define HH 64
#define BT 16   // batch tile per block (MFMA N)
#define HS 72   // h-array stride in bf16 elems (144 B = 16B-aligned b128 frags)
#define FP ((TT - 1) & 1)   // parity of final step (=1)

typedef __bf16 bf16x8 __attribute__((ext_vector_type(8)));
typedef __bf16 bf16x4 __attribute__((ext_vector_type(4)));
typedef float  f32x4  __attribute__((ext_vector_type(4)));

#define MFMA(a,b,c) __builtin_amdgcn_mfma_f32_16x16x32_bf16(a, b, c, 0, 0, 0)

__device__ __forceinline__ float fast_tanh(float a) {
    float e = __builtin_amdgcn_exp2f(a * 2.88539008178f);
    return 1.0f - 2.0f * __builtin_amdgcn_rcpf(e + 1.0f);
}

// 16B-aligned LDS fragment load -> single ds_read_b128
__device__ __forceinline__ bf16x8 ld_frag(const __bf16* p) {
    return *(const bf16x8*)__builtin_assume_aligned(p, 16);
}

__device__ __forceinline__ void cvt_frag(const float* p, bf16x8& hi, bf16x8& lo) {
    f32x4 wa = *(const f32x4*)p;
    f32x4 wb = *(const f32x4*)(p + 4);
    #pragma unroll
    for (int j = 0; j < 8; ++j) {
        float f = (j < 4) ? wa[j] : wb[j - 4];
        __bf16 h = (__bf16)f;
        hi[j] = h;
        lo[j] = (__bf16)(f - (float)h);
    }
}

// 4-wave pipeline: waves 0-1 = layer0 (step p), waves 2-3 = layer1 (step p-1).
// 512 blocks x 4 waves = 2048 waves = 8/CU = 2 waves/SIMD: each SIMD holds two
// waves at different pipeline stages so ds-latency / barrier / transcendental
// stalls of one are covered by the other (round-1 measured 1 wave/SIMD =
// latency-naked, VALUBusy 45%, wall 2772 cyc/phase).
__global__ __launch_bounds__(256, 2)
void rnn_kernel(const float* __restrict__ x,
                const float* __restrict__ h_state,
                const float* __restrict__ W_ih0,
                const float* __restrict__ W_hh0,
                const float* __restrict__ b_ih0,
                const float* __restrict__ b_hh0,
                const float* __restrict__ W_ih1,
                const float* __restrict__ W_hh1,
                const float* __restrict__ b_ih1,
                const float* __restrict__ b_hh1,
                const float* __restrict__ W_out,
                const float* __restrict__ b_out,
                float* __restrict__ out)
{
    __shared__ __align__(16) __bf16 h0hi[2][BT * HS], h0lo[2][BT * HS];
    __shared__ __align__(16) __bf16 h1hi[2][BT * HS], h1lo[2][BT * HS];
    __shared__ float  xs[TT * 17];     // x staged [t][b]
    __shared__ float  outs[TT * 17];   // y staged [t][b]
    __shared__ float  pp[2][2][20];    // projection partials, dbuf by step parity

    const int tid  = threadIdx.x;
    const int w    = tid >> 6;        // 0..3
    const int grp  = w >> 1;          // 0 = layer0 group, 1 = layer1 group
    const int wl   = w & 1;           // unit-half within layer (units 32*wl..)
    const int lane = tid & 63;
    const int col  = lane & 15;       // MFMA col (batch)
    const int q    = lane >> 4;       // quad
    const int b0   = blockIdx.x * BT;

    // ---- A-fragments: [g][kt]; grp0 uses kt 0..1 (Whh0), grp1 kt 0..1=Wih1,
    //      kt 2..3=Whh1. hi/lo split (compensated bf16, identical numerics to
    //      the verified kernel).
    bf16x8 AFh[2][4], AFl[2][4];
    if (grp == 0) {
        #pragma unroll
        for (int g = 0; g < 2; ++g)
        #pragma unroll
        for (int kt = 0; kt < 2; ++kt) {
            const int off = (32 * wl + 16 * g + col) * HH + 32 * kt + 8 * q;
            cvt_frag(W_hh0 + off, AFh[g][kt], AFl[g][kt]);
        }
    } else {
        #pragma unroll
        for (int g = 0; g < 2; ++g)
        #pragma unroll
        for (int kt = 0; kt < 2; ++kt) {
            const int off = (32 * wl + 16 * g + col) * HH + 32 * kt + 8 * q;
            cvt_frag(W_ih1 + off, AFh[g][kt],     AFl[g][kt]);
            cvt_frag(W_hh1 + off, AFh[g][2 + kt], AFl[g][2 + kt]);
        }
    }
    // epilogue scalars: grp0: e0=bias0, e1=Wih0 ; grp1: e0=bias1, e1=Wout
    float e0[2][4], e1[2][4];
    #pragma unroll
    for (int g = 0; g < 2; ++g)
    #pragma unroll
    for (int r = 0; r < 4; ++r) {
        int j = 32 * wl + 16 * g + 4 * q + r;
        if (grp == 0) { e0[g][r] = b_ih0[j] + b_hh0[j]; e1[g][r] = W_ih0[j]; }
        else          { e0[g][r] = b_ih1[j] + b_hh1[j]; e1[g][r] = W_out[j]; }
    }
    const float bout = b_out[0];

    // ---- stage x[b0..b0+15][0..139] into LDS [t][b] (256 threads) ----
    for (int c = 0; c < (TT * BT + 255) / 256; ++c) {
        int i = c * 256 + tid;
        if (i < TT * BT) {
            int t = i >> 4, b = i & 15;
            xs[t * 17 + b] = x[(size_t)(b0 + b) * TT + t];
        }
    }
    // ---- init hidden state ([2,B,H]) into parity-1 buffers (step "-1") ----
    #pragma unroll
    for (int c = 0; c < (BT * HH) / 256; ++c) {
        int i = c * 256 + tid;
        int b = i >> 6, u = i & 63;
        float v0 = h_state[(size_t)(b0 + b) * HH + u];
        float v1 = h_state[(size_t)BB * HH + (size_t)(b0 + b) * HH + u];
        __bf16 c0 = (__bf16)v0;
        h0hi[1][b * HS + u] = c0;
        h0lo[1][b * HS + u] = (__bf16)(v0 - (float)c0);
        __bf16 c1 = (__bf16)v1;
        h1hi[1][b * HS + u] = c1;
        h1lo[1][b * HS + u] = (__bf16)(v1 - (float)c1);
    }
    __syncthreads();

    // ---- pipelined phase loop: p=0..TT+1 ----
    for (int p = 0; p <= TT + 1; ++p) {
        if (grp == 0) {
            if (p < TT) {
                // layer0 step p: read h0(p-1) parity (p+1)&1, write parity p&1
                const int rb = (p + 1) & 1, wb = p & 1;
                bf16x8 Hh[2], Hl[2];
                #pragma unroll
                for (int kt = 0; kt < 2; ++kt) {
                    Hh[kt] = ld_frag(&h0hi[rb][col * HS + 32 * kt + 8 * q]);
                    Hl[kt] = ld_frag(&h0lo[rb][col * HS + 32 * kt + 8 * q]);
                }
                float xt = xs[p * 17 + col];
                #pragma unroll
                for (int g = 0; g < 2; ++g) {
                    f32x4 c0 = {0.f,0.f,0.f,0.f}, c1 = {0.f,0.f,0.f,0.f}, c2 = {0.f,0.f,0.f,0.f};
                    #pragma unroll
                    for (int kt = 0; kt < 2; ++kt) {
                        c0 = MFMA(AFh[g][kt], Hh[kt], c0);   // hi*hi
                        c1 = MFMA(AFh[g][kt], Hl[kt], c1);   // hi*lo
                        c2 = MFMA(AFl[g][kt], Hh[kt], c2);   // lo*hi
                    }
                    f32x4 a = c0 + (c1 + c2);
                    bf16x4 hi4, lo4;
                    #pragma unroll
                    for (int r = 0; r < 4; ++r) {
                        float pre = a[r] + e0[g][r] + e1[g][r] * xt;
                        float hn  = fast_tanh(pre);
                        __bf16 h  = (__bf16)hn;
                        hi4[r] = h;
                        lo4[r] = (__bf16)(hn - (float)h);
                    }
                    *(bf16x4*)(&h0hi[wb][col * HS + 32 * wl + 16 * g + 4 * q]) = hi4;
                    *(bf16x4*)(&h0lo[wb][col * HS + 32 * wl + 16 * g + 4 * q]) = lo4;
                }
            }
            // folder (wave 0): fold step p-2 partials written at phase p-1
            if (w == 0 && p >= 2 && lane < 16) {
                const int s = p - 2, par = p & 1;
                outs[s * 17 + lane] = pp[par][0][lane] + pp[par][1][lane] + bout;
            }
        } else {
            if (p >= 1 && p <= TT) {
                // layer1 step s=p-1: read h0n(s) parity s&1 (written by grp0
                // last phase), h1(s-1) parity (s+1)&1; write h1(s) parity s&1
                const int s   = p - 1;
                const int rb0 = s & 1, rb1 = (s + 1) & 1, wb1 = s & 1;
                bf16x8 Hh[4], Hl[4];
                #pragma unroll
                for (int kt = 0; kt < 2; ++kt) {
                    Hh[kt]     = ld_frag(&h0hi[rb0][col * HS + 32 * kt + 8 * q]);
                    Hl[kt]     = ld_frag(&h0lo[rb0][col * HS + 32 * kt + 8 * q]);
                    Hh[2 + kt] = ld_frag(&h1hi[rb1][col * HS + 32 * kt + 8 * q]);
                    Hl[2 + kt] = ld_frag(&h1lo[rb1][col * HS + 32 * kt + 8 * q]);
                }
                float pr = 0.f;
                #pragma unroll
                for (int g = 0; g < 2; ++g) {
                    f32x4 c0 = {0.f,0.f,0.f,0.f}, c1 = {0.f,0.f,0.f,0.f}, c2 = {0.f,0.f,0.f,0.f};
                    #pragma unroll
                    for (int kt = 0; kt < 4; ++kt) {
                        c0 = MFMA(AFh[g][kt], Hh[kt], c0);
                        c1 = MFMA(AFh[g][kt], Hl[kt], c1);
                        c2 = MFMA(AFl[g][kt], Hh[kt], c2);
                    }
                    f32x4 a = c0 + (c1 + c2);
                    bf16x4 hi4, lo4;
                    #pragma unroll
                    for (int r = 0; r < 4; ++r) {
                        float pre = a[r] + e0[g][r];
                        float hn  = fast_tanh(pre);
                        pr += hn * e1[g][r];
                        __bf16 h = (__bf16)hn;
                        hi4[r] = h;
                        lo4[r] = (__bf16)(hn - (float)h);
                    }
                    *(bf16x4*)(&h1hi[wb1][col * HS + 32 * wl + 16 * g + 4 * q]) = hi4;
                    *(bf16x4*)(&h1lo[wb1][col * HS + 32 * wl + 16 * g + 4 * q]) = lo4;
                }
                pr += __shfl_xor(pr, 16, 64);
                pr += __shfl_xor(pr, 32, 64);
                if (lane < 16) pp[s & 1][wl][lane] = pr;
            }
        }
        __syncthreads();
    }

    // ---- epilogue: staged y -> global; wave w does batches {4*bq + w} ----
    #pragma unroll
    for (int bq = 0; bq < 4; ++bq) {
        int b = 4 * bq + w;
        #pragma unroll
        for (int c = 0; c < 3; ++c) {
            int t = c * 64 + lane;
            if (t < TT) out[(size_t)(b0 + b) * TT + t] = outs[t * 17 + b];
        }
    }
    // ---- h_final: [2,B,H] appended after out[B*T]; final parity FP ----
    const size_t OFF = (size_t)BB * TT;
    #pragma unroll
    for (int c = 0; c < (BT * HH) / 256; ++c) {
        int i = c * 256 + tid;
        int b = i >> 6, u = i & 63;
        float v0 = (float)h0hi[FP][b * HS + u] + (float)h0lo[FP][b * HS + u];
        float v1 = (float)h1hi[FP][b * HS + u] + (float)h1lo[FP][b * HS + u];
        out[OFF + (size_t)(b0 + b) * HH + u] = v0;
        out[OFF + (size_t)BB * HH + (size_t)(b0 + b) * HH + u] = v1;
    }
}

extern "C" void kernel_launch(void* const* d_in, const int* in_sizes, int n_in,
                              void* d_out, int out_size, void* d_ws, size_t ws_size,
                              hipStream_t stream) {
    const float* x      = (const float*)d_in[0];
    const float* hst    = (const float*)d_in[1];
    const float* W_ih0  = (const float*)d_in[2];
    const float* W_hh0  = (const float*)d_in[3];
    const float* b_ih0  = (const float*)d_in[4];
    const float* b_hh0  = (const float*)d_in[5];
    const float* W_ih1  = (const float*)d_in[6];
    const float* W_hh1  = (const float*)d_in[7];
    const float* b_ih1  = (const float*)d_in[8];
    const float* b_hh1  = (const float*)d_in[9];
    const float* W_out  = (const float*)d_in[10];
    const float* b_outp = (const float*)d_in[11];
    float* out = (float*)d_out;

    dim3 grid(BB / BT);   // 512 blocks x 4 waves = 2048 waves = 8/CU (2/SIMD)
    dim3 block(256);
    rnn_kernel<<<grid, block, 0, stream>>>(x, hst, W_ih0, W_hh0, b_ih0, b_hh0,
                                           W_ih1, W_hh1, b_ih1, b_hh1,
                                           W_out, b_outp, out);
}

// Round 4
// 156.450 us; speedup vs baseline: 1.4031x; 1.3491x over previous
//
#include <hip/hip_runtime.h>

#define TT 140
#define BB 8192
#define HH 64
#define BT 16   // batch tile per block (MFMA N)
#define HS 72   // h-array stride in fp16 elems (144 B = 16B-aligned b128 frags)
#define FP ((TT - 1) & 1)   // parity of final step (=1)

typedef _Float16 half8 __attribute__((ext_vector_type(8)));
typedef _Float16 half4 __attribute__((ext_vector_type(4)));
typedef float    f32x4 __attribute__((ext_vector_type(4)));

#define MFMA16(a,b,c) __builtin_amdgcn_mfma_f32_16x16x32_f16(a, b, c, 0, 0, 0)

__device__ __forceinline__ float fast_tanh(float a) {
    float e = __builtin_amdgcn_exp2f(a * 2.88539008178f);
    return 1.0f - 2.0f * __builtin_amdgcn_rcpf(e + 1.0f);
}

// 16B-aligned LDS fragment load -> single ds_read_b128
__device__ __forceinline__ half8 ld_frag(const _Float16* p) {
    return *(const half8*)__builtin_assume_aligned(p, 16);
}

// load 8 f32 weights, convert to fp16 (single precision — fp16 lo-residuals
// of |W|<0.125 are denormal, so compensation is structurally useless here)
__device__ __forceinline__ half8 cvt_frag16(const float* p) {
    f32x4 wa = *(const f32x4*)p;
    f32x4 wb = *(const f32x4*)(p + 4);
    half8 h;
    #pragma unroll
    for (int j = 0; j < 8; ++j) h[j] = (_Float16)((j < 4) ? wa[j] : wb[j - 4]);
    return h;
}

// 4-wave pipeline: waves 0-1 = layer0 (step p), waves 2-3 = layer1 (step p-1).
// fp16 single-precision state+weights (issue-bound kernel: round-2/3 counters
// show VALUBusy ~42% invariant to occupancy => SIMD issue port saturated; the
// bf16 hi/lo compensation tripled MFMAs and doubled LDS traffic + epilogue).
__global__ __launch_bounds__(256, 2)
void rnn_kernel(const float* __restrict__ x,
                const float* __restrict__ h_state,
                const float* __restrict__ W_ih0,
                const float* __restrict__ W_hh0,
                const float* __restrict__ b_ih0,
                const float* __restrict__ b_hh0,
                const float* __restrict__ W_ih1,
                const float* __restrict__ W_hh1,
                const float* __restrict__ b_ih1,
                const float* __restrict__ b_hh1,
                const float* __restrict__ W_out,
                const float* __restrict__ b_out,
                float* __restrict__ out)
{
    __shared__ __align__(16) _Float16 h0f[2][BT * HS];
    __shared__ __align__(16) _Float16 h1f[2][BT * HS];
    __shared__ float xs[TT * 17];        // x staged [t][b]
    __shared__ float pps[TT * 34];       // projection partials [t][wl*17 + b]

    const int tid  = threadIdx.x;
    const int w    = tid >> 6;        // 0..3
    const int grp  = w >> 1;          // 0 = layer0 group, 1 = layer1 group
    const int wl   = w & 1;           // unit-half within layer (units 32*wl..)
    const int lane = tid & 63;
    const int col  = lane & 15;       // MFMA col (batch)
    const int q    = lane >> 4;       // quad
    const int b0   = blockIdx.x * BT;

    // ---- A-fragments (fp16): grp0: AF[g][kt]=Whh0; grp1: AF=Wih1, AG=Whh1
    half8 AF[2][2], AG[2][2];
    #pragma unroll
    for (int g = 0; g < 2; ++g)
    #pragma unroll
    for (int kt = 0; kt < 2; ++kt) {
        const int off = (32 * wl + 16 * g + col) * HH + 32 * kt + 8 * q;
        if (grp == 0) {
            AF[g][kt] = cvt_frag16(W_hh0 + off);
            AG[g][kt] = AF[g][kt];   // unused, keep defined
        } else {
            AF[g][kt] = cvt_frag16(W_ih1 + off);
            AG[g][kt] = cvt_frag16(W_hh1 + off);
        }
    }
    // epilogue scalars: grp0: e0=bias0, e1=Wih0 ; grp1: e0=bias1, e1=Wout
    float e0[2][4], e1[2][4];
    #pragma unroll
    for (int g = 0; g < 2; ++g)
    #pragma unroll
    for (int r = 0; r < 4; ++r) {
        int j = 32 * wl + 16 * g + 4 * q + r;
        if (grp == 0) { e0[g][r] = b_ih0[j] + b_hh0[j]; e1[g][r] = W_ih0[j]; }
        else          { e0[g][r] = b_ih1[j] + b_hh1[j]; e1[g][r] = W_out[j]; }
    }
    const float bout = b_out[0];

    // ---- stage x[b0..b0+15][0..139] into LDS [t][b] (256 threads) ----
    for (int c = 0; c < (TT * BT + 255) / 256; ++c) {
        int i = c * 256 + tid;
        if (i < TT * BT) {
            int t = i >> 4, b = i & 15;
            xs[t * 17 + b] = x[(size_t)(b0 + b) * TT + t];
        }
    }
    // ---- init hidden state ([2,B,H]) into parity-1 buffers (step "-1") ----
    #pragma unroll
    for (int c = 0; c < (BT * HH) / 256; ++c) {
        int i = c * 256 + tid;
        int b = i >> 6, u = i & 63;
        h0f[1][b * HS + u] = (_Float16)h_state[(size_t)(b0 + b) * HH + u];
        h1f[1][b * HS + u] = (_Float16)h_state[(size_t)BB * HH + (size_t)(b0 + b) * HH + u];
    }
    __syncthreads();

    // ---- pipelined phase loop: p=0..TT ----
    for (int p = 0; p <= TT; ++p) {
        if (grp == 0) {
            if (p < TT) {
                // layer0 step p: read h0(p-1) parity (p+1)&1, write parity p&1
                const int rb = (p + 1) & 1, wb = p & 1;
                half8 Hf[2];
                #pragma unroll
                for (int kt = 0; kt < 2; ++kt)
                    Hf[kt] = ld_frag(&h0f[rb][col * HS + 32 * kt + 8 * q]);
                float xt = xs[p * 17 + col];
                #pragma unroll
                for (int g = 0; g < 2; ++g) {
                    f32x4 c = {0.f, 0.f, 0.f, 0.f};
                    c = MFMA16(AF[g][0], Hf[0], c);
                    c = MFMA16(AF[g][1], Hf[1], c);
                    half4 h4;
                    #pragma unroll
                    for (int r = 0; r < 4; ++r) {
                        float pre = c[r] + e0[g][r] + e1[g][r] * xt;
                        h4[r] = (_Float16)fast_tanh(pre);
                    }
                    *(half4*)(&h0f[wb][col * HS + 32 * wl + 16 * g + 4 * q]) = h4;
                }
            }
        } else {
            if (p >= 1) {
                // layer1 step s=p-1: read h0n(s) parity s&1 (written by grp0
                // last phase), h1(s-1) parity (s+1)&1; write h1(s) parity s&1
                const int s   = p - 1;
                const int rb0 = s & 1, rb1 = (s + 1) & 1, wb1 = s & 1;
                half8 H0f[2], H1f[2];
                #pragma unroll
                for (int kt = 0; kt < 2; ++kt) {
                    H0f[kt] = ld_frag(&h0f[rb0][col * HS + 32 * kt + 8 * q]);
                    H1f[kt] = ld_frag(&h1f[rb1][col * HS + 32 * kt + 8 * q]);
                }
                float pr = 0.f;
                #pragma unroll
                for (int g = 0; g < 2; ++g) {
                    f32x4 ci = {0.f, 0.f, 0.f, 0.f}, ch = {0.f, 0.f, 0.f, 0.f};
                    ci = MFMA16(AF[g][0], H0f[0], ci);
                    ci = MFMA16(AF[g][1], H0f[1], ci);
                    ch = MFMA16(AG[g][0], H1f[0], ch);
                    ch = MFMA16(AG[g][1], H1f[1], ch);
                    f32x4 a = ci + ch;
                    half4 h4;
                    #pragma unroll
                    for (int r = 0; r < 4; ++r) {
                        float pre = a[r] + e0[g][r];
                        float hn  = fast_tanh(pre);
                        pr += hn * e1[g][r];
                        h4[r] = (_Float16)hn;
                    }
                    *(half4*)(&h1f[wb1][col * HS + 32 * wl + 16 * g + 4 * q]) = h4;
                }
                pr += __shfl_xor(pr, 16, 64);
                pr += __shfl_xor(pr, 32, 64);
                if (lane < 16) pps[s * 34 + wl * 17 + lane] = pr;
            }
        }
        __syncthreads();
    }

    // ---- epilogue: fold partials + store y; wave w does batches {4*bq+w} ----
    #pragma unroll
    for (int bq = 0; bq < 4; ++bq) {
        int b = 4 * bq + w;
        #pragma unroll
        for (int c = 0; c < 3; ++c) {
            int t = c * 64 + lane;
            if (t < TT)
                out[(size_t)(b0 + b) * TT + t] =
                    pps[t * 34 + b] + pps[t * 34 + 17 + b] + bout;
        }
    }
    // ---- h_final: [2,B,H] appended after out[B*T]; final parity FP ----
    const size_t OFF = (size_t)BB * TT;
    #pragma unroll
    for (int c = 0; c < (BT * HH) / 256; ++c) {
        int i = c * 256 + tid;
        int b = i >> 6, u = i & 63;
        out[OFF + (size_t)(b0 + b) * HH + u] = (float)h0f[FP][b * HS + u];
        out[OFF + (size_t)BB * HH + (size_t)(b0 + b) * HH + u] = (float)h1f[FP][b * HS + u];
    }
}

extern "C" void kernel_launch(void* const* d_in, const int* in_sizes, int n_in,
                              void* d_out, int out_size, void* d_ws, size_t ws_size,
                              hipStream_t stream) {
    const float* x      = (const float*)d_in[0];
    const float* hst    = (const float*)d_in[1];
    const float* W_ih0  = (const float*)d_in[2];
    const float* W_hh0  = (const float*)d_in[3];
    const float* b_ih0  = (const float*)d_in[4];
    const float* b_hh0  = (const float*)d_in[5];
    const float* W_ih1  = (const float*)d_in[6];
    const float* W_hh1  = (const float*)d_in[7];
    const float* b_ih1  = (const float*)d_in[8];
    const float* b_hh1  = (const float*)d_in[9];
    const float* W_out  = (const float*)d_in[10];
    const float* b_outp = (const float*)d_in[11];
    float* out = (float*)d_out;

    dim3 grid(BB / BT);   // 512 blocks x 4 waves = 2048 waves = 8/CU (2/SIMD)
    dim3 block(256);
    rnn_kernel<<<grid, block, 0, stream>>>(x, hst, W_ih0, W_hh0, b_ih0, b_hh0,
                                           W_ih1, W_hh1, b_ih1, b_hh1,
                                           W_out, b_outp, out);
}

// Round 5
// 151.095 us; speedup vs baseline: 1.4528x; 1.0354x over previous
//
#include <hip/hip_runtime.h>

#define TT 140
#define BB 8192
#define HH 64
#define BT 16   // batch tile per block (MFMA N)
#define HS 72   // h-array stride in fp16 elems (144 B = 16B-aligned b128 frags)
#define FP ((TT - 1) & 1)   // parity of final step (=1)

typedef _Float16 half8 __attribute__((ext_vector_type(8)));
typedef _Float16 half4 __attribute__((ext_vector_type(4)));
typedef float    f32x4 __attribute__((ext_vector_type(4)));

#define MFMA16(a,b,c) __builtin_amdgcn_mfma_f32_16x16x32_f16(a, b, c, 0, 0, 0)

__device__ __forceinline__ float fast_tanh(float a) {
    float e = __builtin_amdgcn_exp2f(a * 2.88539008178f);
    return 1.0f - 2.0f * __builtin_amdgcn_rcpf(e + 1.0f);
}

// 16B-aligned LDS fragment load -> single ds_read_b128
__device__ __forceinline__ half8 ld_frag(const _Float16* p) {
    return *(const half8*)__builtin_assume_aligned(p, 16);
}

// load 8 f32 weights, convert to fp16
__device__ __forceinline__ half8 cvt_frag16(const float* p) {
    f32x4 wa = *(const f32x4*)p;
    f32x4 wb = *(const f32x4*)(p + 4);
    half8 h;
    #pragma unroll
    for (int j = 0; j < 8; ++j) h[j] = (_Float16)((j < 4) ? wa[j] : wb[j - 4]);
    return h;
}

// Uniform-wave pipeline: 4 identical waves per block; wave w owns unit-quarter
// 16w..16w+15 of BOTH layers (L0 at step p, L1 at step p-1). Round-4 counters
// showed role-split waves collide same-role on SIMDs (heavy L1 SIMDs pace the
// barrier, L0 SIMDs idle, VALUBusy 48% / wall 1507 cyc/phase). Merged roles:
// per-SIMD balance by construction + the h0 fragments are read ONCE and feed
// both the L0 recurrence MFMA and L1's ih1 MFMA (they are the same data).
__global__ __launch_bounds__(256, 2)
void rnn_kernel(const float* __restrict__ x,
                const float* __restrict__ h_state,
                const float* __restrict__ W_ih0,
                const float* __restrict__ W_hh0,
                const float* __restrict__ b_ih0,
                const float* __restrict__ b_hh0,
                const float* __restrict__ W_ih1,
                const float* __restrict__ W_hh1,
                const float* __restrict__ b_ih1,
                const float* __restrict__ b_hh1,
                const float* __restrict__ W_out,
                const float* __restrict__ b_out,
                float* __restrict__ out)
{
    __shared__ __align__(16) _Float16 h0f[2][BT * HS];
    __shared__ __align__(16) _Float16 h1f[2][BT * HS];
    __shared__ float xs[TT * 17];        // x staged [t][b]
    __shared__ float pps[TT * 68];       // projection partials [t][w*17 + b]

    const int tid  = threadIdx.x;
    const int w    = tid >> 6;        // 0..3 = unit-quarter
    const int lane = tid & 63;
    const int col  = lane & 15;       // MFMA col (batch)
    const int q    = lane >> 4;       // quad
    const int b0   = blockIdx.x * BT;

    // ---- A-fragments (fp16): rows 16w+col of Whh0 / Wih1 / Whh1 ----
    half8 A0[2], AI[2], AH[2];
    #pragma unroll
    for (int kt = 0; kt < 2; ++kt) {
        const int off = (16 * w + col) * HH + 32 * kt + 8 * q;
        A0[kt] = cvt_frag16(W_hh0 + off);
        AI[kt] = cvt_frag16(W_ih1 + off);
        AH[kt] = cvt_frag16(W_hh1 + off);
    }
    // epilogue scalars for this wave's quarter (units 16w+4q+r)
    float e00[4], e10[4], e01[4], e11[4];
    #pragma unroll
    for (int r = 0; r < 4; ++r) {
        int j = 16 * w + 4 * q + r;
        e00[r] = b_ih0[j] + b_hh0[j];  e10[r] = W_ih0[j];
        e01[r] = b_ih1[j] + b_hh1[j];  e11[r] = W_out[j];
    }
    const float bout = b_out[0];

    // ---- stage x[b0..b0+15][0..139] into LDS [t][b] (256 threads) ----
    for (int c = 0; c < (TT * BT + 255) / 256; ++c) {
        int i = c * 256 + tid;
        if (i < TT * BT) {
            int t = i >> 4, b = i & 15;
            xs[t * 17 + b] = x[(size_t)(b0 + b) * TT + t];
        }
    }
    // ---- init hidden state ([2,B,H]) into parity-1 buffers (step "-1") ----
    #pragma unroll
    for (int c = 0; c < (BT * HH) / 256; ++c) {
        int i = c * 256 + tid;
        int b = i >> 6, u = i & 63;
        h0f[1][b * HS + u] = (_Float16)h_state[(size_t)(b0 + b) * HH + u];
        h1f[1][b * HS + u] = (_Float16)h_state[(size_t)BB * HH + (size_t)(b0 + b) * HH + u];
    }
    __syncthreads();

    // ---- pipelined phase loop: p=0..TT ----
    for (int p = 0; p <= TT; ++p) {
        const int rb = (p + 1) & 1;   // h0(p-1) parity == h0n(s=p-1) parity
        const int wb = p & 1;         // h0(p) write parity == h1(p-2) parity
        // All 4 fragment reads hoisted: none alias this phase's writes
        // (h0 writes parity wb, reads parity rb; h1 writes rb, reads wb).
        half8 H0a = ld_frag(&h0f[rb][col * HS + 8 * q]);
        half8 H0b = ld_frag(&h0f[rb][col * HS + 32 + 8 * q]);
        half8 H1a = ld_frag(&h1f[wb][col * HS + 8 * q]);
        half8 H1b = ld_frag(&h1f[wb][col * HS + 32 + 8 * q]);
        float xt  = xs[p * 17 + col];

        if (p < TT) {
            // layer0 step p (quarter w): h0n = tanh(Whh0*h0 + b + Wih0*x)
            f32x4 c = {0.f, 0.f, 0.f, 0.f};
            c = MFMA16(A0[0], H0a, c);
            c = MFMA16(A0[1], H0b, c);
            half4 h4;
            #pragma unroll
            for (int r = 0; r < 4; ++r) {
                float pre = c[r] + e00[r] + e10[r] * xt;
                h4[r] = (_Float16)fast_tanh(pre);
            }
            *(half4*)(&h0f[wb][col * HS + 16 * w + 4 * q]) = h4;
        }
        if (p >= 1) {
            // layer1 step s=p-1 (quarter w): reuses H0a/H0b (= h0n(s))
            f32x4 ci = {0.f, 0.f, 0.f, 0.f}, ch = {0.f, 0.f, 0.f, 0.f};
            ci = MFMA16(AI[0], H0a, ci);
            ci = MFMA16(AI[1], H0b, ci);
            ch = MFMA16(AH[0], H1a, ch);
            ch = MFMA16(AH[1], H1b, ch);
            f32x4 a = ci + ch;
            float pr = 0.f;
            half4 h4;
            #pragma unroll
            for (int r = 0; r < 4; ++r) {
                float pre = a[r] + e01[r];
                float hn  = fast_tanh(pre);
                pr += hn * e11[r];
                h4[r] = (_Float16)hn;
            }
            *(half4*)(&h1f[rb][col * HS + 16 * w + 4 * q]) = h4;
            pr += __shfl_xor(pr, 16, 64);
            pr += __shfl_xor(pr, 32, 64);
            if (lane < 16) pps[(p - 1) * 68 + w * 17 + lane] = pr;
        }
        __syncthreads();
    }

    // ---- epilogue: fold 4 quarter-partials + store y; wave w -> batches 4bq+w ----
    #pragma unroll
    for (int bq = 0; bq < 4; ++bq) {
        int b = 4 * bq + w;
        #pragma unroll
        for (int c = 0; c < 3; ++c) {
            int t = c * 64 + lane;
            if (t < TT)
                out[(size_t)(b0 + b) * TT + t] =
                    pps[t * 68 + b] + pps[t * 68 + 17 + b]
                  + pps[t * 68 + 34 + b] + pps[t * 68 + 51 + b] + bout;
        }
    }
    // ---- h_final: [2,B,H] appended after out[B*T]; final parity FP ----
    const size_t OFF = (size_t)BB * TT;
    #pragma unroll
    for (int c = 0; c < (BT * HH) / 256; ++c) {
        int i = c * 256 + tid;
        int b = i >> 6, u = i & 63;
        out[OFF + (size_t)(b0 + b) * HH + u] = (float)h0f[FP][b * HS + u];
        out[OFF + (size_t)BB * HH + (size_t)(b0 + b) * HH + u] = (float)h1f[FP][b * HS + u];
    }
}

extern "C" void kernel_launch(void* const* d_in, const int* in_sizes, int n_in,
                              void* d_out, int out_size, void* d_ws, size_t ws_size,
                              hipStream_t stream) {
    const float* x      = (const float*)d_in[0];
    const float* hst    = (const float*)d_in[1];
    const float* W_ih0  = (const float*)d_in[2];
    const float* W_hh0  = (const float*)d_in[3];
    const float* b_ih0  = (const float*)d_in[4];
    const float* b_hh0  = (const float*)d_in[5];
    const float* W_ih1  = (const float*)d_in[6];
    const float* W_hh1  = (const float*)d_in[7];
    const float* b_ih1  = (const float*)d_in[8];
    const float* b_hh1  = (const float*)d_in[9];
    const float* W_out  = (const float*)d_in[10];
    const float* b_outp = (const float*)d_in[11];
    float* out = (float*)d_out;

    dim3 grid(BB / BT);   // 512 blocks x 4 waves = 2048 waves = 8/CU (2/SIMD)
    dim3 block(256);
    rnn_kernel<<<grid, block, 0, stream>>>(x, hst, W_ih0, W_hh0, b_ih0, b_hh0,
                                           W_ih1, W_hh1, b_ih1, b_hh1,
                                           W_out, b_outp, out);
}